// Round 7
// baseline (302.032 us; speedup 1.0000x reference)
//
#include <hip/hip_runtime.h>
#include <stdint.h>

typedef float f32x4 __attribute__((ext_vector_type(4)));
typedef __bf16 bf16x8 __attribute__((ext_vector_type(8)));
typedef unsigned short ushortx8 __attribute__((ext_vector_type(8)));

#define D_DIM 512
#define KGC 10
#define NCLU 8
#define BATCH 32
#define WPOS 250
#define WPAD 256
#define KDIM 3584   // 512*7
#define MROWS 522
#define BM 128      // block m-tile (4 slices cover exactly 512 feat rows)
#define BN 128      // block n-tile
#define NS 56       // K steps (KDIM/64), full K per block
#define NT 64       // n-tiles of 128 (N = 8192)
#define KSG 56
#define NTOT 8192
// XS: bf16 X pre-arranged in MFMA B-fragment lane order.
// unit u = ks*512 + nf*64 + lane (16B each) holds
// X[n = nt*128 + nf*16 + (lane&15)][k = ksg*64 + ks*32 + (lane>>4)*8 + e], e=0..7
#define XTILE 8192  // ushorts per (nt,ksg) tile

__device__ __forceinline__ float bf2f(unsigned short u) {
  union { unsigned int i; float f; } v; v.i = ((unsigned int)u) << 16; return v.f;
}
__device__ __forceinline__ unsigned short f2bf(float f) {
  union { float f; unsigned int i; } v; v.f = f;
  unsigned int r = v.i + 0x7FFFu + ((v.i >> 16) & 1u);
  return (unsigned short)(r >> 16);
}

__device__ __forceinline__ void load_lds16(const void* g, void* l) {
  __builtin_amdgcn_global_load_lds(
      (const __attribute__((address_space(1))) void*)g,
      (__attribute__((address_space(3))) void*)l, 16, 0, 0);
}

// ---------------- prep2: W bf16 rows + bias  |  X transpose->XS + assign partials LGP ----------------
// blocks 0..521: W row / bias. blocks 522..4105: X tile (nt, ksg):
//   coalesced float2 loads of x -> LDS fp32 [64][130] -> (a) XS fragment-order bf16 units,
//   (b) LGP[ksg][10][8192] partial assign logits (fp32 dot with aw over this tile's 64 k's).
__global__ __launch_bounds__(256) void prep2_kernel(
    const float* __restrict__ fw, const float* __restrict__ fb,
    const float* __restrict__ aw, const float* __restrict__ ab,
    const float* __restrict__ x,
    unsigned short* __restrict__ Wcat, float* __restrict__ bcat,
    unsigned short* __restrict__ XS, float* __restrict__ LGP) {
  const int bid = blockIdx.x;
  const int tid = threadIdx.x;
  if (bid < MROWS) {
    int r = bid;
    if (r < D_DIM) {
      unsigned short* dst = Wcat + (size_t)r * KDIM;
      const float* src = fw + (size_t)r * KDIM;
      for (int i = tid; i < KDIM / 4; i += 256) {
        float4 v = ((const float4*)src)[i];
        ushort4 o; o.x = f2bf(v.x); o.y = f2bf(v.y); o.z = f2bf(v.z); o.w = f2bf(v.w);
        ((ushort4*)dst)[i] = o;
      }
    }
    if (tid == 0) bcat[r] = (r < D_DIM) ? fb[r] : ab[r - D_DIM];
    return;
  }
  // ---- X tile ----
  __shared__ float Xt[64][130];   // padded: phase-2/3 reads land 2-way max (free)
  __shared__ float Awl[KGC * 64];
  const int xt = bid - MROWS;
  const int nt = xt / KSG, ksg = xt - nt * KSG;
  const int b = nt >> 1, c0 = (nt & 1) * 128;
  const int k0 = ksg * 64;
  // phase 1a: coalesced loads, 8B/lane: row = (tid>>6)+4p, float2 index tid&63
  {
    const int l2 = tid & 63, r0 = tid >> 6;
#pragma unroll
    for (int p = 0; p < 16; p++) {
      const int row = r0 + p * 4;
      const int gc = c0 + l2 * 2;
      const float* xp = x + ((size_t)b * KDIM + k0 + row) * WPOS + gc;
      float v0 = 0.f, v1 = 0.f;
      if (gc + 1 < WPOS) { float2 v = *(const float2*)xp; v0 = v.x; v1 = v.y; }
      else if (gc < WPOS) { v0 = xp[0]; }
      Xt[row][l2 * 2] = v0;
      Xt[row][l2 * 2 + 1] = v1;
    }
  }
  // phase 1b: aw chunk -> LDS (10 rows x 64 k)
#pragma unroll
  for (int i = 0; i < 3; i++) {
    int q = tid + 256 * i;
    if (q < KGC * 64) Awl[q] = aw[(size_t)(q >> 6) * KDIM + k0 + (q & 63)];
  }
  __syncthreads();
  // phase 2: XS fragment-order bf16 units (16B/lane coalesced stores)
  {
    unsigned short* tb = XS + (size_t)(nt * KSG + ksg) * XTILE;
#pragma unroll
    for (int i = 0; i < 4; i++) {
      const int L = tid + 256 * i;
      const int ks = L >> 9, nf = (L >> 6) & 7, lane = L & 63;
      const int fr = lane & 15, kg = lane >> 4;
      ushortx8 pk;
#pragma unroll
      for (int e = 0; e < 8; e++)
        pk[e] = f2bf(Xt[ks * 32 + kg * 8 + e][nf * 16 + fr]);
      *(ushortx8*)&tb[(size_t)L * 8] = pk;
    }
  }
  // phase 3: assign partials (fp32): LGP[ksg][j][n] = sum_kk aw[j][k0+kk]*x[..][kk][n]
#pragma unroll
  for (int i = 0; i < 5; i++) {
    const int idx = tid + 256 * i;           // 0..1279
    const int j = idx >> 7, c = idx & 127;
    float s = 0.f;
#pragma unroll 8
    for (int kk = 0; kk < 64; kk++) s += Awl[j * 64 + kk] * Xt[kk][c];
    LGP[((size_t)ksg * KGC + j) * NTOT + nt * 128 + c] = s;
  }
}

// ---------------- fused full-K GEMM (feat only): Y[b][m][w](bf16) = relu(W @ x + b) ----------------
// 512 thr (8 waves 4m x 2n, wave 32x64, r=4: each ds_read_b128 feeds 4 MFMA).
// grid (64 nt, 4 mh) = 256 blocks, BM=128 -> ZERO M-padding waste.
// 4-deep W LDS pipeline (64 KB), issue-then-wait counted vmcnt(10) (2 dma + 8 X-loads
// per thread per step, uniform), bare s_barrier + sched_barrier, setprio on MFMA.
__global__ __launch_bounds__(512, 2) void gemm_fused(
    const unsigned short* __restrict__ XS, const unsigned short* __restrict__ Wcat,
    const float* __restrict__ bcat, unsigned short* __restrict__ Y) {
  __shared__ __align__(16) unsigned short Wl[4][BM * 64];  // 4 x 16,384 B swizzled
  const int tid = threadIdx.x;
  const int nt = blockIdx.x, mh = blockIdx.y;
  // ids = nt + 64*mh: the 4 mh-sharers of an XS slice differ by 64 -> same XCD.
  const int lane = tid & 63, wv = tid >> 6;     // 8 waves
  const int wm = wv >> 1, wn = wv & 1;          // 4m x 2n -> wave 32x64
  const int fr = lane & 15, kg = lane >> 4;
  const int sx = fr & 7;
  const unsigned short* Wg = Wcat + (size_t)mh * BM * KDIM;
  const unsigned short* xsb = XS + (size_t)nt * (KSG * XTILE) + (wn * 2048 + lane * 8);

  // W lds-dma: 128 rows x 8 octets = 1024 slots = EXACTLY 2/thread (uniform vmcnt).
  // LDS dest linear; global source pre-swizzled (both-sides rule).
  auto stageW = [&](int st, int buf) {
#pragma unroll
    for (int it = 0; it < 2; it++) {
      int s = it * 512 + tid;
      int row = s >> 3, p = s & 7;
      int blk = p ^ (row & 7);
      load_lds16(Wg + (size_t)row * KDIM + st * 64 + blk * 8, &Wl[buf][s * 8]);
    }
  };
#define LOADX(st, XR)                                                        \
  {                                                                          \
    const unsigned short* p_ = xsb + (size_t)(st) * XTILE;                   \
    XR[0] = *(const bf16x8*)(p_);                                            \
    XR[1] = *(const bf16x8*)(p_ + 512);                                      \
    XR[2] = *(const bf16x8*)(p_ + 1024);                                     \
    XR[3] = *(const bf16x8*)(p_ + 1536);                                     \
    XR[4] = *(const bf16x8*)(p_ + 4096);                                     \
    XR[5] = *(const bf16x8*)(p_ + 4096 + 512);                               \
    XR[6] = *(const bf16x8*)(p_ + 4096 + 1024);                              \
    XR[7] = *(const bf16x8*)(p_ + 4096 + 1536);                              \
  }

  f32x4 acc[2][4];
  const f32x4 zero = {0.f, 0.f, 0.f, 0.f};
#pragma unroll
  for (int f = 0; f < 2; f++)
#pragma unroll
    for (int j = 0; j < 4; j++) acc[f][j] = zero;

#define COMPUTE(BUF, XR)                                                     \
  {                                                                          \
    __builtin_amdgcn_s_setprio(1);                                           \
    _Pragma("unroll")                                                        \
    for (int ks = 0; ks < 2; ks++) {                                         \
      const int off = ((ks * 4 + kg) ^ sx) * 8;                              \
      _Pragma("unroll")                                                      \
      for (int f = 0; f < 2; f++) {                                          \
        bf16x8 af = *(const bf16x8*)&Wl[BUF][(wm * 32 + f * 16 + fr) * 64 + off]; \
        acc[f][0] = __builtin_amdgcn_mfma_f32_16x16x32_bf16(af, XR[ks * 4 + 0], acc[f][0], 0, 0, 0); \
        acc[f][1] = __builtin_amdgcn_mfma_f32_16x16x32_bf16(af, XR[ks * 4 + 1], acc[f][1], 0, 0, 0); \
        acc[f][2] = __builtin_amdgcn_mfma_f32_16x16x32_bf16(af, XR[ks * 4 + 2], acc[f][2], 0, 0, 0); \
        acc[f][3] = __builtin_amdgcn_mfma_f32_16x16x32_bf16(af, XR[ks * 4 + 3], acc[f][3], 0, 0, 0); \
      }                                                                      \
    }                                                                        \
    __builtin_amdgcn_s_setprio(0);                                           \
  }

  bf16x8 XA[8], XB[8];

  // prologue: dma steps 0,1; X(0) -> A
  stageW(0, 0);
  stageW(1, 1);
  LOADX(0, XA);

  for (int t = 0; t < NS; t += 2) {
    // step u = t (even): consume buf t&3 / XA
    if (t + 2 < NS) stageW(t + 2, (t + 2) & 3);
    LOADX(t + 1, XB);                              // t+1 <= 55 always
    if (t + 2 < NS) { asm volatile("s_waitcnt vmcnt(10)"); }
    else            { asm volatile("s_waitcnt vmcnt(8)"); }
    __builtin_amdgcn_s_barrier();
    __builtin_amdgcn_sched_barrier(0);
    COMPUTE((t) & 3, XA);
    // step u = t+1 (odd): consume buf (t+1)&3 / XB
    if (t + 3 < NS) stageW(t + 3, (t + 3) & 3);
    if (t + 2 < NS) LOADX(t + 2, XA);
    if (t + 3 < NS)      { asm volatile("s_waitcnt vmcnt(10)"); }
    else if (t + 2 < NS) { asm volatile("s_waitcnt vmcnt(8)"); }
    else                 { asm volatile("s_waitcnt vmcnt(0)"); }
    __builtin_amdgcn_s_barrier();
    __builtin_amdgcn_sched_barrier(0);
    COMPUTE((t + 1) & 3, XB);
  }
#undef LOADX
#undef COMPUTE

  // fused epilogue: C/D frag col = lane&15 (n), row = kg*4 + r. All rows are feat -> ReLU.
  const int bb = (nt * BN) >> 8;
  const int cbase = (nt * BN) & 255;
  unsigned short* Yb = Y + (size_t)bb * D_DIM * WPAD;
#pragma unroll
  for (int f = 0; f < 2; f++) {
    const int m0 = mh * BM + wm * 32 + f * 16 + kg * 4;
    const float b0 = bcat[m0], b1 = bcat[m0 + 1], b2 = bcat[m0 + 2], b3 = bcat[m0 + 3];
#pragma unroll
    for (int j = 0; j < 4; j++) {
      const int c = cbase + wn * 64 + j * 16 + fr;
      Yb[(size_t)(m0 + 0) * WPAD + c] = f2bf(fmaxf(acc[f][j][0] + b0, 0.f));
      Yb[(size_t)(m0 + 1) * WPAD + c] = f2bf(fmaxf(acc[f][j][1] + b1, 0.f));
      Yb[(size_t)(m0 + 2) * WPAD + c] = f2bf(fmaxf(acc[f][j][2] + b2, 0.f));
      Yb[(size_t)(m0 + 3) * WPAD + c] = f2bf(fmaxf(acc[f][j][3] + b3, 0.f));
    }
  }
}

// ---------------- epilogue: softmax(from LGP fp32), agg, centroid subtract, L2-normalize ----------------
__global__ __launch_bounds__(512) void epi_kernel(
    const unsigned short* __restrict__ Y, const float* __restrict__ LGP,
    const float* __restrict__ bcat, const float* __restrict__ cent,
    float* __restrict__ out) {
  __shared__ float soft[WPAD];
  __shared__ float red[8];
  const int b = blockIdx.x >> 3, k = blockIdx.x & 7;
  const int tid = threadIdx.x;
  const unsigned short* Yb = Y + (size_t)b * D_DIM * WPAD;

  float sv = 0.f;
  if (tid < WPOS) {
    float lg[KGC];
#pragma unroll
    for (int j = 0; j < KGC; j++) lg[j] = bcat[D_DIM + j];
    const float* base = LGP + (size_t)b * 256 + tid;
    for (int kq = 0; kq < KSG; kq++) {
      const float* pp = base + (size_t)kq * KGC * NTOT;
#pragma unroll
      for (int j = 0; j < KGC; j++) lg[j] += pp[(size_t)j * NTOT];
    }
    float mx = -1e30f;
#pragma unroll
    for (int j = 0; j < KGC; j++) mx = fmaxf(mx, lg[j]);
    float s = 0.f, ek = 0.f;
#pragma unroll
    for (int j = 0; j < KGC; j++) {
      float e = __expf(lg[j] - mx);
      s += e;
      if (j == k) ek = e;
    }
    sv = ek / s;
  }
  if (tid < WPAD) soft[tid] = sv;   // tids 250..255 write 0
  __syncthreads();

  float v = sv;
#pragma unroll
  for (int o = 32; o > 0; o >>= 1) v += __shfl_down(v, o, 64);
  if ((tid & 63) == 0) red[tid >> 6] = v;
  __syncthreads();
  float ssum = 0.f;
#pragma unroll
  for (int i = 0; i < 8; i++) ssum += red[i];

  float a[8];
#pragma unroll
  for (int u = 0; u < 8; u++) a[u] = 0.f;
  const unsigned short* row = Yb + (size_t)tid * WPAD;
  for (int w = 0; w < WPAD; w += 8) {
    ushortx8 f0 = *(const ushortx8*)(row + w);
    float4 s0 = *(const float4*)&soft[w];
    float4 s1 = *(const float4*)&soft[w + 4];
    a[0] += bf2f(f0[0]) * s0.x;
    a[1] += bf2f(f0[1]) * s0.y;
    a[2] += bf2f(f0[2]) * s0.z;
    a[3] += bf2f(f0[3]) * s0.w;
    a[4] += bf2f(f0[4]) * s1.x;
    a[5] += bf2f(f0[5]) * s1.y;
    a[6] += bf2f(f0[6]) * s1.z;
    a[7] += bf2f(f0[7]) * s1.w;
  }
  float asum = ((a[0] + a[1]) + (a[2] + a[3])) + ((a[4] + a[5]) + (a[6] + a[7]));
  float c = asum - cent[(size_t)tid * KGC + k] * ssum;

  __syncthreads();
  float q = c * c;
#pragma unroll
  for (int o = 32; o > 0; o >>= 1) q += __shfl_down(q, o, 64);
  if ((tid & 63) == 0) red[tid >> 6] = q;
  __syncthreads();
  float nsum = 0.f;
#pragma unroll
  for (int i = 0; i < 8; i++) nsum += red[i];
  float norm = sqrtf(nsum);
  float inv = 1.f / fmaxf(norm, 1e-12f);

  float* ob = out + (size_t)b * (NCLU * D_DIM) + (size_t)k * D_DIM;
  ob[tid] = c * inv;
}

extern "C" void kernel_launch(void* const* d_in, const int* in_sizes, int n_in,
                              void* d_out, int out_size, void* d_ws, size_t ws_size,
                              hipStream_t stream) {
  const float* x  = (const float*)d_in[0];
  const float* fw = (const float*)d_in[1];
  const float* fb = (const float*)d_in[2];
  const float* aw = (const float*)d_in[3];
  const float* ab = (const float*)d_in[4];
  const float* ce = (const float*)d_in[5];
  float* out = (float*)d_out;
  char* ws = (char*)d_ws;

  const size_t WC_BYTES  = (size_t)D_DIM * KDIM * 2;          //  3,670,016
  const size_t BC_BYTES  = 4096;
  const size_t XS_BYTES  = (size_t)NT * KSG * XTILE * 2;      // 58,720,256
  const size_t LGP_BYTES = (size_t)KSG * KGC * NTOT * 4;      // 18,350,080
  unsigned short* Wc  = (unsigned short*)(ws);
  float*          bc  = (float*)(ws + WC_BYTES);
  unsigned short* XSp = (unsigned short*)(ws + WC_BYTES + BC_BYTES);
  float*          LGp = (float*)(ws + WC_BYTES + BC_BYTES + XS_BYTES);
  unsigned short* Yv  = (unsigned short*)(ws + WC_BYTES + BC_BYTES + XS_BYTES + LGP_BYTES);
  // total ws use ~89.1 MB (Y = 32*512*256*2 = 8,388,608)

  prep2_kernel<<<MROWS + NT * KSG, 256, 0, stream>>>(fw, fb, aw, ab, x, Wc, bc, XSp, LGp);
  gemm_fused<<<dim3(NT, 4), 512, 0, stream>>>(XSp, Wc, bc, Yv);
  epi_kernel<<<BATCH * NCLU, 512, 0, stream>>>(Yv, LGp, bc, ce, out);
}

// Round 9
// 284.342 us; speedup vs baseline: 1.0622x; 1.0622x over previous
//
#include <hip/hip_runtime.h>
#include <stdint.h>

typedef float f32x4 __attribute__((ext_vector_type(4)));
typedef __bf16 bf16x8 __attribute__((ext_vector_type(8)));
typedef unsigned short ushortx8 __attribute__((ext_vector_type(8)));

#define D_DIM 512
#define KGC 10
#define NCLU 8
#define BATCH 32
#define WPOS 250
#define WPAD 256
#define KDIM 3584   // 512*7
#define MROWS 522   // 512 feat + 10 assign
#define MPAD 528    // Wcat/Y rows (522 real + 6 zero pad)
#define BM 128      // main block m-tile (4 slices cover 512 feat rows)
#define BN 128      // block n-tile
#define NS 56       // K steps (KDIM/64), full K per block
#define NT 64       // n-tiles of 128 (N = 8192)
#define KSG 56
// XS: bf16 X pre-arranged in MFMA B-fragment lane order.
// unit u = ks*512 + nf*64 + lane (16B each) holds
// X[n = nt*128 + nf*16 + (lane&15)][k = ksg*64 + ks*32 + (lane>>4)*8 + e], e=0..7
#define XTILE 8192  // ushorts per (nt,ksg) tile

__device__ __forceinline__ float bf2f(unsigned short u) {
  union { unsigned int i; float f; } v; v.i = ((unsigned int)u) << 16; return v.f;
}
__device__ __forceinline__ unsigned short f2bf(float f) {
  union { float f; unsigned int i; } v; v.f = f;
  unsigned int r = v.i + 0x7FFFu + ((v.i >> 16) & 1u);
  return (unsigned short)(r >> 16);
}

__device__ __forceinline__ void load_lds16(const void* g, void* l) {
  __builtin_amdgcn_global_load_lds(
      (const __attribute__((address_space(1))) void*)g,
      (__attribute__((address_space(3))) void*)l, 16, 0, 0);
}

// ---------------- prep2: W bf16 rows (528) + bias | X transpose -> XS ----------------
// blocks 0..527: Wcat row r (rows 522..527 zero). blocks 528..4111: X tile (nt,ksg):
// coalesced float2 x loads -> bf16 LDS [64][136] (XOR col swizzle) -> XS 16B stores.
// LDS 17.4 KB -> 8 blocks/CU (vs R7's fp32 tile at 4).
__global__ __launch_bounds__(256) void prep2_kernel(
    const float* __restrict__ fw, const float* __restrict__ fb,
    const float* __restrict__ aw, const float* __restrict__ ab,
    const float* __restrict__ x,
    unsigned short* __restrict__ Wcat, float* __restrict__ bcat,
    unsigned short* __restrict__ XS) {
  const int bid = blockIdx.x;
  const int tid = threadIdx.x;
  if (bid < MPAD) {
    int r = bid;
    unsigned short* dst = Wcat + (size_t)r * KDIM;
    const float* src = (r < D_DIM) ? (fw + (size_t)r * KDIM)
                     : (r < MROWS) ? (aw + (size_t)(r - D_DIM) * KDIM)
                                   : nullptr;
    for (int i = tid; i < KDIM / 4; i += 256) {
      unsigned short o0 = 0, o1 = 0, o2 = 0, o3 = 0;
      if (src) {
        float4 v = ((const float4*)src)[i];
        o0 = f2bf(v.x); o1 = f2bf(v.y); o2 = f2bf(v.z); o3 = f2bf(v.w);
      }
      ushort4 o; o.x = o0; o.y = o1; o.z = o2; o.w = o3;
      ((ushort4*)dst)[i] = o;
    }
    if (tid == 0)
      bcat[r] = (r < D_DIM) ? fb[r] : (r < MROWS ? ab[r - D_DIM] : 0.f);
    return;
  }
  // ---- X tile ----
  __shared__ unsigned short Xt[64][136];   // bf16, col swizzled: col ^ (((row>>3)&3)<<4)
  const int xt = bid - MPAD;
  const int nt = xt / KSG, ksg = xt - nt * KSG;
  const int b = nt >> 1, c0 = (nt & 1) * 128;
  const int k0 = ksg * 64;
  // phase 1: coalesced float2 loads (8B/lane), convert, swizzled ushort2 LDS store.
  {
    const int l2 = tid & 63, r0 = tid >> 6;
#pragma unroll
    for (int p = 0; p < 16; p++) {
      const int row = r0 + p * 4;
      const int gc = c0 + l2 * 2;
      const float* xp = x + ((size_t)b * KDIM + k0 + row) * WPOS + gc;
      float v0 = 0.f, v1 = 0.f;
      if (gc + 1 < WPOS) { float2 v = *(const float2*)xp; v0 = v.x; v1 = v.y; }
      else if (gc < WPOS) { v0 = xp[0]; }
      const int key = (row >> 3) & 3;                     // uniform per instr
      ushort2 o; o.x = f2bf(v0); o.y = f2bf(v1);
      *(ushort2*)&Xt[row][(2 * l2) ^ (key << 4)] = o;     // bank-perfect
    }
  }
  __syncthreads();
  // phase 2: fragment-order bf16 units (16B/lane coalesced global stores).
  // read col' = (nf*16+fr) ^ (kg<<4): 64 lanes -> 32 banks, 2 lanes/bank same word.
  {
    unsigned short* tb = XS + (size_t)(nt * KSG + ksg) * XTILE;
#pragma unroll
    for (int i = 0; i < 4; i++) {
      const int L = tid + 256 * i;
      const int ks = L >> 9, nf = (L >> 6) & 7, lane = L & 63;
      const int fr = lane & 15, kg = lane >> 4;
      const int colp = (nf * 16 + fr) ^ (kg << 4);
      ushortx8 pk;
#pragma unroll
      for (int e = 0; e < 8; e++) pk[e] = Xt[ks * 32 + kg * 8 + e][colp];
      *(ushortx8*)&tb[(size_t)L * 8] = pk;
    }
  }
}

// ---------------- fused full-K GEMM: Y[b][m][w](bf16) = act(W @ x + bias) ----------------
// grid (64 nt, 5 mh). mh 0..3: feat rows (BM=128, 8 waves 4m x 2n, wave 32x64).
// 4-deep W LDS pipeline; per step: LOADX FIRST then stageW -> in-order vmcnt keeps the
// dma in flight 2 compute phases; steady wait vmcnt(12), tails 10/0. setprio on MFMA.
// mh==4: assign rows 512..527 -- NO LDS, NO barriers: A-frags gathered from L2-hot Wcat,
// B-frags from XS, 2 MFMA/step/wave; 64 tiny blocks.
__global__ __launch_bounds__(512) void gemm_fused(
    const unsigned short* __restrict__ XS, const unsigned short* __restrict__ Wcat,
    const float* __restrict__ bcat, unsigned short* __restrict__ Y) {
  __shared__ __align__(16) unsigned short Wl[4][BM * 64];  // 4 x 16,384 B swizzled
  const int tid = threadIdx.x;
  const int nt = blockIdx.x, mh = blockIdx.y;
  const int lane = tid & 63, wv = tid >> 6;
  const int fr = lane & 15, kg = lane >> 4;
  const int bb = (nt * BN) >> 8;
  const int cbase = (nt * BN) & 255;
  unsigned short* Yb = Y + (size_t)bb * MPAD * WPAD;

  if (mh == 4) {
    // ---- assign slice: rows 512..527, wave wv covers cols wv*16..+15 ----
    const unsigned short* xb2 = XS + (size_t)nt * (KSG * XTILE) + (size_t)(wv * 64 + lane) * 8;
    const unsigned short* Wg2 = Wcat + (size_t)(D_DIM + fr) * KDIM + kg * 8;
    f32x4 acc = {0.f, 0.f, 0.f, 0.f};
#pragma unroll 4
    for (int st = 0; st < NS; st++) {
      bf16x8 a0 = *(const bf16x8*)(Wg2 + st * 64);
      bf16x8 a1 = *(const bf16x8*)(Wg2 + st * 64 + 32);
      bf16x8 b0 = *(const bf16x8*)(xb2 + (size_t)st * XTILE);
      bf16x8 b1 = *(const bf16x8*)(xb2 + (size_t)st * XTILE + 4096);
      acc = __builtin_amdgcn_mfma_f32_16x16x32_bf16(a0, b0, acc, 0, 0, 0);
      acc = __builtin_amdgcn_mfma_f32_16x16x32_bf16(a1, b1, acc, 0, 0, 0);
    }
    const int c = cbase + wv * 16 + fr;
#pragma unroll
    for (int r = 0; r < 4; r++) {
      const int m = D_DIM + kg * 4 + r;          // 512..527 (pad rows: zero W, zero bias)
      Yb[(size_t)m * WPAD + c] = f2bf(acc[r] + bcat[m]);
    }
    return;
  }

  // ---- main feat slice ----
  const int wm = wv >> 1, wn = wv & 1;          // 4m x 2n -> wave 32x64
  const int sx = fr & 7;
  const unsigned short* Wg = Wcat + (size_t)mh * BM * KDIM;
  const unsigned short* xsb = XS + (size_t)nt * (KSG * XTILE) + (wn * 2048 + lane * 8);

  // W lds-dma: 128 rows x 8 octets = 1024 slots = EXACTLY 2/thread (uniform vmcnt).
  auto stageW = [&](int st, int buf) {
#pragma unroll
    for (int it = 0; it < 2; it++) {
      int s = it * 512 + tid;
      int row = s >> 3, p = s & 7;
      int blk = p ^ (row & 7);
      load_lds16(Wg + (size_t)row * KDIM + st * 64 + blk * 8, &Wl[buf][s * 8]);
    }
  };
#define LOADX(st, XR)                                                        \
  {                                                                          \
    const unsigned short* p_ = xsb + (size_t)(st) * XTILE;                   \
    XR[0] = *(const bf16x8*)(p_);                                            \
    XR[1] = *(const bf16x8*)(p_ + 512);                                      \
    XR[2] = *(const bf16x8*)(p_ + 1024);                                     \
    XR[3] = *(const bf16x8*)(p_ + 1536);                                     \
    XR[4] = *(const bf16x8*)(p_ + 4096);                                     \
    XR[5] = *(const bf16x8*)(p_ + 4096 + 512);                               \
    XR[6] = *(const bf16x8*)(p_ + 4096 + 1024);                              \
    XR[7] = *(const bf16x8*)(p_ + 4096 + 1536);                              \
  }

  f32x4 acc[2][4];
  const f32x4 zero = {0.f, 0.f, 0.f, 0.f};
#pragma unroll
  for (int f = 0; f < 2; f++)
#pragma unroll
    for (int j = 0; j < 4; j++) acc[f][j] = zero;

#define COMPUTE(BUF, XR)                                                     \
  {                                                                          \
    __builtin_amdgcn_s_setprio(1);                                           \
    _Pragma("unroll")                                                        \
    for (int ks = 0; ks < 2; ks++) {                                         \
      const int off = ((ks * 4 + kg) ^ sx) * 8;                              \
      _Pragma("unroll")                                                      \
      for (int f = 0; f < 2; f++) {                                          \
        bf16x8 af = *(const bf16x8*)&Wl[BUF][(wm * 32 + f * 16 + fr) * 64 + off]; \
        acc[f][0] = __builtin_amdgcn_mfma_f32_16x16x32_bf16(af, XR[ks * 4 + 0], acc[f][0], 0, 0, 0); \
        acc[f][1] = __builtin_amdgcn_mfma_f32_16x16x32_bf16(af, XR[ks * 4 + 1], acc[f][1], 0, 0, 0); \
        acc[f][2] = __builtin_amdgcn_mfma_f32_16x16x32_bf16(af, XR[ks * 4 + 2], acc[f][2], 0, 0, 0); \
        acc[f][3] = __builtin_amdgcn_mfma_f32_16x16x32_bf16(af, XR[ks * 4 + 3], acc[f][3], 0, 0, 0); \
      }                                                                      \
    }                                                                        \
    __builtin_amdgcn_s_setprio(0);                                           \
  }

  bf16x8 XA[8], XB[8];

  // prologue: dma steps 0,1; X(0) -> A
  stageW(0, 0);
  stageW(1, 1);
  LOADX(0, XA);

  // Step u: {LOADX(u+1) FIRST, then stageW(u+2)} -> at the wait, oldest = X(u), then
  // dma(u+1): vmcnt(12) drains X(u) (+dma(u) already gone) but keeps dma(u+1),
  // X(u+1), dma(u+2) in flight. dma lives ~2 compute phases. 4 bufs + 1 barrier/step:
  // write (u+2) after barrier(u-1) ensured all waves finished compute(u-2). [rule #18
  // fencing: sched_barrier(0) after s_barrier pins ds_reads below.]
#define STEP(u, XC, XN)                                                       \
  {                                                                           \
    if ((u) + 1 < NS) LOADX((u) + 1, XN);                                     \
    if ((u) + 2 < NS) stageW((u) + 2, ((u) + 2) & 3);                         \
    if ((u) + 2 < NS)      { asm volatile("s_waitcnt vmcnt(12)" ::: "memory"); } \
    else if ((u) + 1 < NS) { asm volatile("s_waitcnt vmcnt(10)" ::: "memory"); } \
    else                   { asm volatile("s_waitcnt vmcnt(0)" ::: "memory"); }  \
    __builtin_amdgcn_s_barrier();                                             \
    __builtin_amdgcn_sched_barrier(0);                                        \
    COMPUTE(((u) & 3), XC);                                                   \
  }

  for (int t = 0; t < NS; t += 2) {
    STEP(t, XA, XB);
    STEP(t + 1, XB, XA);
  }
#undef STEP
#undef LOADX
#undef COMPUTE

  // fused epilogue: C/D frag col = lane&15 (n), row = kg*4 + r. All feat rows -> ReLU.
#pragma unroll
  for (int f = 0; f < 2; f++) {
    const int m0 = mh * BM + wm * 32 + f * 16 + kg * 4;
    const float b0 = bcat[m0], b1 = bcat[m0 + 1], b2 = bcat[m0 + 2], b3 = bcat[m0 + 3];
#pragma unroll
    for (int j = 0; j < 4; j++) {
      const int c = cbase + wn * 64 + j * 16 + fr;
      Yb[(size_t)(m0 + 0) * WPAD + c] = f2bf(fmaxf(acc[f][j][0] + b0, 0.f));
      Yb[(size_t)(m0 + 1) * WPAD + c] = f2bf(fmaxf(acc[f][j][1] + b1, 0.f));
      Yb[(size_t)(m0 + 2) * WPAD + c] = f2bf(fmaxf(acc[f][j][2] + b2, 0.f));
      Yb[(size_t)(m0 + 3) * WPAD + c] = f2bf(fmaxf(acc[f][j][3] + b3, 0.f));
    }
  }
}

// ---------------- epilogue: softmax, agg, subtract centroids*s_sum, L2-normalize ----------------
// 512 thr (8 waves, 1 d-row per thread), float4 broadcast soft reads,
// 8 independent accumulators to break the fma dependency chain.
__global__ __launch_bounds__(512) void epi_kernel(
    const unsigned short* __restrict__ Y, const float* __restrict__ cent,
    float* __restrict__ out) {
  __shared__ float soft[WPAD];
  __shared__ float red[8];
  const int b = blockIdx.x >> 3, k = blockIdx.x & 7;
  const int tid = threadIdx.x;
  const unsigned short* Yb = Y + (size_t)b * MPAD * WPAD;

  float sv = 0.f;
  if (tid < WPOS) {
    float lg[KGC];
    float mx = -1e30f;
#pragma unroll
    for (int j = 0; j < KGC; j++) {
      lg[j] = bf2f(Yb[(size_t)(D_DIM + j) * WPAD + tid]);
      mx = fmaxf(mx, lg[j]);
    }
    float s = 0.f, ek = 0.f;
#pragma unroll
    for (int j = 0; j < KGC; j++) {
      float e = __expf(lg[j] - mx);
      s += e;
      if (j == k) ek = e;
    }
    sv = ek / s;
  }
  if (tid < WPAD) soft[tid] = sv;   // tids 250..255 write 0
  __syncthreads();

  float v = sv;
#pragma unroll
  for (int o = 32; o > 0; o >>= 1) v += __shfl_down(v, o, 64);
  if ((tid & 63) == 0) red[tid >> 6] = v;
  __syncthreads();
  float ssum = 0.f;
#pragma unroll
  for (int i = 0; i < 8; i++) ssum += red[i];

  float a[8];
#pragma unroll
  for (int u = 0; u < 8; u++) a[u] = 0.f;
  const unsigned short* row = Yb + (size_t)tid * WPAD;
  for (int w = 0; w < WPAD; w += 8) {
    ushortx8 f0 = *(const ushortx8*)(row + w);
    float4 s0 = *(const float4*)&soft[w];
    float4 s1 = *(const float4*)&soft[w + 4];
    a[0] += bf2f(f0[0]) * s0.x;
    a[1] += bf2f(f0[1]) * s0.y;
    a[2] += bf2f(f0[2]) * s0.z;
    a[3] += bf2f(f0[3]) * s0.w;
    a[4] += bf2f(f0[4]) * s1.x;
    a[5] += bf2f(f0[5]) * s1.y;
    a[6] += bf2f(f0[6]) * s1.z;
    a[7] += bf2f(f0[7]) * s1.w;
  }
  float asum = ((a[0] + a[1]) + (a[2] + a[3])) + ((a[4] + a[5]) + (a[6] + a[7]));
  float c = asum - cent[(size_t)tid * KGC + k] * ssum;

  __syncthreads();
  float q = c * c;
#pragma unroll
  for (int o = 32; o > 0; o >>= 1) q += __shfl_down(q, o, 64);
  if ((tid & 63) == 0) red[tid >> 6] = q;
  __syncthreads();
  float nsum = 0.f;
#pragma unroll
  for (int i = 0; i < 8; i++) nsum += red[i];
  float norm = sqrtf(nsum);
  float inv = 1.f / fmaxf(norm, 1e-12f);

  float* ob = out + (size_t)b * (NCLU * D_DIM) + (size_t)k * D_DIM;
  ob[tid] = c * inv;
}

extern "C" void kernel_launch(void* const* d_in, const int* in_sizes, int n_in,
                              void* d_out, int out_size, void* d_ws, size_t ws_size,
                              hipStream_t stream) {
  const float* x  = (const float*)d_in[0];
  const float* fw = (const float*)d_in[1];
  const float* fb = (const float*)d_in[2];
  const float* aw = (const float*)d_in[3];
  const float* ab = (const float*)d_in[4];
  const float* ce = (const float*)d_in[5];
  float* out = (float*)d_out;
  char* ws = (char*)d_ws;

  const size_t WC_BYTES  = (size_t)MPAD * KDIM * 2;           //  3,784,704
  const size_t BC_BYTES  = 4096;
  const size_t XS_BYTES  = (size_t)NT * KSG * XTILE * 2;      // 58,720,256
  unsigned short* Wc  = (unsigned short*)(ws);
  float*          bc  = (float*)(ws + WC_BYTES);
  unsigned short* XSp = (unsigned short*)(ws + WC_BYTES + BC_BYTES);
  unsigned short* Yv  = (unsigned short*)(ws + WC_BYTES + BC_BYTES + XS_BYTES);
  // total ws use ~71 MB (Y = 32*528*256*2 = 8,650,752)

  prep2_kernel<<<MPAD + NT * KSG, 256, 0, stream>>>(fw, fb, aw, ab, x, Wc, bc, XSp);
  gemm_fused<<<dim3(NT, 5), 512, 0, stream>>>(XSp, Wc, bc, Yv);
  epi_kernel<<<BATCH * NCLU, 512, 0, stream>>>(Yv, ce, out);
}